// Round 18
// baseline (399.379 us; speedup 1.0000x reference)
//
#include <hip/hip_runtime.h>
#include <hip/hip_bf16.h>

// DecoderBlock: B=128, T=S=256, C=384, H=6, D=64. fp32 in/out, bf16 MFMA compute.
#define BB 128
#define TT 256
#define CC 384
#define HH 6
#define DD 64
#define NTOK 32768  // B*T

typedef __attribute__((ext_vector_type(8))) short short8;
typedef __attribute__((ext_vector_type(4))) float f32x4;

__device__ __forceinline__ unsigned short f2bf(float f) {
  union { float f; unsigned int u; } v; v.f = f;
  unsigned int r = v.u + 0x7fff + ((v.u >> 16) & 1);  // RNE
  return (unsigned short)(r >> 16);
}

__device__ __forceinline__ void glds16(const void* g, void* l) {
  __builtin_amdgcn_global_load_lds((const __attribute__((address_space(1))) void*)g,
                                   (__attribute__((address_space(3))) void*)l, 16, 0, 0);
}

__device__ __forceinline__ void vm_drain() {
  asm volatile("s_waitcnt vmcnt(0)" ::: "memory");
  __builtin_amdgcn_sched_barrier(0);
}

// ---------------- weight packing: LDS-tiled 64x64 transposes (full-line writes) ----
__global__ __launch_bounds__(256) void pack_t_k(
    const float* __restrict__ wq1, const float* __restrict__ wk1, const float* __restrict__ wv1,
    const float* __restrict__ wq2, const float* __restrict__ wk2, const float* __restrict__ wv2,
    const float* __restrict__ proj1_w, const float* __restrict__ proj2_w,
    const float* __restrict__ ffn_w1, const float* __restrict__ ffn_w2,
    unsigned short* __restrict__ W) {
  __shared__ unsigned short tile[64 * 72];
  const int id = blockIdx.x;
  const int tid = threadIdx.x;
  const float* src;
  unsigned short* dst;
  int ldIn, ldOut, i0, j0;
  if (id < 216) {  // 6 headstack weights x 6 heads x 6 tile-rows (384x64 per head)
    int w = id / 36, rem = id - w * 36;
    int h = rem / 6, tr = rem - h * 6;
    const float* bases[6] = {wq1, wk1, wv1, wq2, wk2, wv2};
    const int dstOff[6] = {0, 147456, 294912, 442368, 589824, 737280};
    src = bases[w] + h * 24576;
    dst = W + dstOff[w] + h * 24576;
    ldIn = 64; ldOut = 384; i0 = tr * 64; j0 = 0;
  } else if (id < 288) {  // proj1/proj2: 384x384, 6x6 tiles
    int t = id - 216;
    int which = t / 36; t -= which * 36;
    int tr = t / 6, tc = t - tr * 6;
    src = which ? proj2_w : proj1_w;
    dst = W + (which ? 1032192 : 884736);
    ldIn = 384; ldOut = 384; i0 = tr * 64; j0 = tc * 64;
  } else if (id < 432) {  // ffn_w1: 384x1536, 6x24 tiles
    int t = id - 288;
    int tr = t / 24, tc = t - tr * 24;
    src = ffn_w1; dst = W + 1179648;
    ldIn = 1536; ldOut = 384; i0 = tr * 64; j0 = tc * 64;
  } else {  // ffn_w2: 1536x384, 24x6 tiles
    int t = id - 432;
    int tr = t / 6, tc = t - tr * 6;
    src = ffn_w2; dst = W + 1769472;
    ldIn = 384; ldOut = 1536; i0 = tr * 64; j0 = tc * 64;
  }
#pragma unroll
  for (int p = 0; p < 4; ++p) {
    int chunk = p * 256 + tid;  // 1024 float4 reads
    int r = chunk >> 4, c4 = chunk & 15;
    float4 f = *(const float4*)&src[(size_t)(i0 + r) * ldIn + j0 + c4 * 4];
    tile[(c4 * 4 + 0) * 72 + r] = f2bf(f.x);
    tile[(c4 * 4 + 1) * 72 + r] = f2bf(f.y);
    tile[(c4 * 4 + 2) * 72 + r] = f2bf(f.z);
    tile[(c4 * 4 + 3) * 72 + r] = f2bf(f.w);
  }
  __syncthreads();
#pragma unroll
  for (int p = 0; p < 2; ++p) {
    int chunk = p * 256 + tid;  // 512 uint4 writes
    int j = chunk >> 3, i8 = chunk & 7;
    *(uint4*)&dst[(size_t)(j0 + j) * ldOut + i0 + i8 * 8] = *(const uint4*)&tile[j * 72 + i8 * 8];
  }
}

// ---------------- layernorm (fp32 in -> bf16 out), float2-vectorized ----------------
__global__ __launch_bounds__(256) void ln_k(const float* __restrict__ x,
                                            unsigned short* __restrict__ out,
                                            const float* __restrict__ gamma,
                                            const float* __restrict__ beta) {
  int row = blockIdx.x * 4 + (threadIdx.x >> 6);
  int lane = threadIdx.x & 63;
  const float2* xr = (const float2*)(x + (size_t)row * CC);
  float2 v[3];
  float s = 0.f;
#pragma unroll
  for (int j = 0; j < 3; ++j) { v[j] = xr[j * 64 + lane]; s += v[j].x + v[j].y; }
#pragma unroll
  for (int m = 1; m < 64; m <<= 1) s += __shfl_xor(s, m);
  float mu = s * (1.0f / CC);
  float vs = 0.f;
#pragma unroll
  for (int j = 0; j < 3; ++j) {
    float dx = v[j].x - mu, dy = v[j].y - mu;
    vs += dx * dx + dy * dy;
  }
#pragma unroll
  for (int m = 1; m < 64; m <<= 1) vs += __shfl_xor(vs, m);
  float rs = rsqrtf(vs * (1.0f / CC) + 1e-5f);
  unsigned int* orow = (unsigned int*)(out + (size_t)row * CC);
#pragma unroll
  for (int j = 0; j < 3; ++j) {
    int cidx = j * 64 + lane;
    float2 gmm = ((const float2*)gamma)[cidx];
    float2 bt = ((const float2*)beta)[cidx];
    unsigned int lo = f2bf((v[j].x - mu) * rs * gmm.x + bt.x);
    unsigned int hi = f2bf((v[j].y - mu) * rs * gmm.y + bt.y);
    orow[cidx] = lo | (hi << 16);
  }
}

// ---------------- GEMM: C(MxN) = A(MxK) * Bt(NxK)^T (bf16 outputs) ----------
// BMx128 tile, 4 waves, single-buffer glds staging, full drain per step.
// EPI 0: bf16 out; EPI 1: bf16 relu+bias (LDS-transpose full-line epilogue).
template <int EPI, bool AF32, int BM>
__global__ __launch_bounds__(256) void gemm_k(const void* __restrict__ Ap, int lda,
                                              const unsigned short* __restrict__ Bt, int ldb,
                                              void* __restrict__ Cp, int ldc,
                                              const float* __restrict__ bias,
                                              int K, int nx) {
  constexpr int MI = BM / 32;
  constexpr int APASS = BM * 8 / 256;
  __shared__ unsigned short smem[BM * 64 + 8192];
  unsigned short* sA = smem;
  unsigned short* sB = smem + BM * 64;
  const int tid = threadIdx.x;
  const int chunkg = gridDim.x >> 3;
  const int wg = blockIdx.x;
  const int lg = (wg & 7) * chunkg + (wg >> 3);
  const int bx = lg % nx, by = lg / nx;
  const int m0 = by * BM;
  const int n0 = bx * 128;
  const int wid = tid >> 6, lane = tid & 63;
  const int wr = wid >> 1, wc = wid & 1;
  const int g = lane >> 4, c = lane & 15;

  f32x4 acc[MI][4] = {};
  float biasr[4];
  if (EPI >= 1) {
#pragma unroll
    for (int ni = 0; ni < 4; ++ni) biasr[ni] = bias[n0 + wc * 64 + ni * 16 + c];
  }

  const int nt = K >> 6;
  for (int t = 0; t < nt; ++t) {
    const int k0 = t * 64;
    if constexpr (!AF32) {
#pragma unroll
      for (int p = 0; p < APASS; ++p) {
        int chunk = p * 256 + tid;
        int row = chunk >> 3, grp = chunk & 7;
        const unsigned short* Ab = (const unsigned short*)Ap;
        glds16(&Ab[(size_t)(m0 + row) * lda + k0 + ((grp ^ (row & 7)) << 3)], &sA[chunk * 8]);
      }
    } else {
#pragma unroll
      for (int p = 0; p < APASS; ++p) {
        int chunk = p * 256 + tid;
        int row = chunk >> 3, grp = chunk & 7;
        int dst = row * 64 + ((grp ^ (row & 7)) << 3);
        const float* Af = (const float*)Ap + (size_t)(m0 + row) * lda + k0 + grp * 8;
        float4 f0 = *(const float4*)Af;
        float4 f1 = *(const float4*)(Af + 4);
        union { unsigned short h[8]; uint4 u; } t2;
        t2.h[0] = f2bf(f0.x); t2.h[1] = f2bf(f0.y); t2.h[2] = f2bf(f0.z); t2.h[3] = f2bf(f0.w);
        t2.h[4] = f2bf(f1.x); t2.h[5] = f2bf(f1.y); t2.h[6] = f2bf(f1.z); t2.h[7] = f2bf(f1.w);
        *(uint4*)&sA[dst] = t2.u;
      }
    }
#pragma unroll
    for (int p = 0; p < 4; ++p) {
      int chunk = p * 256 + tid;
      int row = chunk >> 3, grp = chunk & 7;
      glds16(&Bt[(size_t)(n0 + row) * ldb + k0 + ((grp ^ (row & 7)) << 3)], &sB[chunk * 8]);
    }
    vm_drain();
    __syncthreads();
#pragma unroll
    for (int kk = 0; kk < 2; ++kk) {
      short8 a[MI], b[4];
#pragma unroll
      for (int mi = 0; mi < MI; ++mi) {
        int r = wr * (BM / 2) + mi * 16 + c;
        a[mi] = *(const short8*)&sA[r * 64 + (((kk * 4 + g) ^ (r & 7)) << 3)];
      }
#pragma unroll
      for (int ni = 0; ni < 4; ++ni) {
        int rb = wc * 64 + ni * 16 + c;
        b[ni] = *(const short8*)&sB[rb * 64 + (((kk * 4 + g) ^ (rb & 7)) << 3)];
      }
#pragma unroll
      for (int mi = 0; mi < MI; ++mi)
#pragma unroll
        for (int ni = 0; ni < 4; ++ni)
          acc[mi][ni] = __builtin_amdgcn_mfma_f32_16x16x32_bf16(a[mi], b[ni], acc[mi][ni], 0, 0, 0);
    }
    __syncthreads();
  }

#pragma unroll
  for (int mi = 0; mi < MI; ++mi)
#pragma unroll
    for (int ni = 0; ni < 4; ++ni)
#pragma unroll
      for (int i = 0; i < 4; ++i) {
        int row = wr * (BM / 2) + mi * 16 + g * 4 + i;
        int col = wc * 64 + ni * 16 + c;
        float v = acc[mi][ni][i];
        if (EPI == 1) v = fmaxf(v + biasr[ni], 0.f);
        int gsw = (col >> 3) ^ ((row >> 2) & 7);
        smem[row * 128 + gsw * 8 + (col & 7)] = f2bf(v);
      }
  __syncthreads();
#pragma unroll
  for (int it = 0; it < BM / 16; ++it) {
    int chunk = it * 256 + tid;
    int row = chunk >> 4, c16 = chunk & 15;
    int gsw = c16 ^ ((row >> 2) & 7);
    *(uint4*)&((unsigned short*)Cp)[(size_t)(m0 + row) * ldc + n0 + c16 * 8] =
        *(const uint4*)&smem[row * 128 + gsw * 8];
  }
}

// ---------------- ffn2: 64x192 tile (2 N-panels: h1 logical reads 3x -> 2x) --------
// 4 waves in 2x2 (each 32x96, acc[2][6]). sA 8KB + sB 24KB = 32KB (same occupancy
// as BM=64/BN=128). out = acc + b2 + res via 32-row fp32 bounce halves,
// full-line float4 stores + coalesced res loads.
__global__ __launch_bounds__(256) void ffn2_k(const unsigned short* __restrict__ h1,
                                              const unsigned short* __restrict__ W2t,
                                              float* __restrict__ out,
                                              const float* __restrict__ b2,
                                              const float* __restrict__ res) {
  __shared__ unsigned short smem[16384];  // 32KB: sA[64][64] + sB[192][64] / bounce [32][196]f32
  unsigned short* sA = smem;
  unsigned short* sB = smem + 4096;
  const int tid = threadIdx.x;
  const int wg = blockIdx.x;
  const int lg = (wg & 7) * (gridDim.x >> 3) + (wg >> 3);
  const int bx = lg & 1, by = lg >> 1;  // consecutive lg share the A-panel (same XCD)
  const int m0 = by * 64;
  const int n0 = bx * 192;
  const int wid = tid >> 6, lane = tid & 63;
  const int wr = wid >> 1, wc = wid & 1;
  const int g = lane >> 4, c = lane & 15;

  f32x4 acc[2][6] = {};
  float biasr[6];
#pragma unroll
  for (int ni = 0; ni < 6; ++ni) biasr[ni] = b2[n0 + wc * 96 + ni * 16 + c];

  for (int t = 0; t < 24; ++t) {
    const int k0 = t * 64;
#pragma unroll
    for (int p = 0; p < 2; ++p) {  // A: 512 chunks
      int chunk = p * 256 + tid;
      int row = chunk >> 3, grp = chunk & 7;
      glds16(&h1[(size_t)(m0 + row) * 1536 + k0 + ((grp ^ (row & 7)) << 3)], &sA[chunk * 8]);
    }
#pragma unroll
    for (int p = 0; p < 6; ++p) {  // B: 1536 chunks
      int chunk = p * 256 + tid;
      int row = chunk >> 3, grp = chunk & 7;
      glds16(&W2t[(size_t)(n0 + row) * 1536 + k0 + ((grp ^ (row & 7)) << 3)], &sB[chunk * 8]);
    }
    vm_drain();
    __syncthreads();
#pragma unroll
    for (int kk = 0; kk < 2; ++kk) {
      short8 a[2], b[6];
#pragma unroll
      for (int mi = 0; mi < 2; ++mi) {
        int r = wr * 32 + mi * 16 + c;
        a[mi] = *(const short8*)&sA[r * 64 + (((kk * 4 + g) ^ (r & 7)) << 3)];
      }
#pragma unroll
      for (int ni = 0; ni < 6; ++ni) {
        int rb = wc * 96 + ni * 16 + c;
        b[ni] = *(const short8*)&sB[rb * 64 + (((kk * 4 + g) ^ (rb & 7)) << 3)];
      }
#pragma unroll
      for (int mi = 0; mi < 2; ++mi)
#pragma unroll
        for (int ni = 0; ni < 6; ++ni)
          acc[mi][ni] = __builtin_amdgcn_mfma_f32_16x16x32_bf16(a[mi], b[ni], acc[mi][ni], 0, 0, 0);
    }
    __syncthreads();
  }

  // epilogue: two 32-row halves through fp32 bounce [32][196]
  float* smf = (float*)smem;
#pragma unroll
  for (int h = 0; h < 2; ++h) {
    if (h) __syncthreads();
    if (wr == h) {
#pragma unroll
      for (int mi = 0; mi < 2; ++mi)
#pragma unroll
        for (int ni = 0; ni < 6; ++ni)
#pragma unroll
          for (int i = 0; i < 4; ++i) {
            int row = mi * 16 + g * 4 + i;  // 0..31
            int col = wc * 96 + ni * 16 + c;
            smf[row * 196 + col] = acc[mi][ni][i] + biasr[ni];
          }
    }
    __syncthreads();
#pragma unroll
    for (int it = 0; it < 6; ++it) {
      int chunk = it * 256 + tid;  // 1536 float4 (32 rows x 48 groups)
      int row = chunk / 48, gg = chunk % 48;
      float4 v = *(const float4*)&smf[row * 196 + gg * 4];
      int grow = m0 + h * 32 + row;
      float4 r = *(const float4*)&res[(size_t)grow * 384 + n0 + gg * 4];
      float4 o;
      o.x = v.x + r.x; o.y = v.y + r.y; o.z = v.z + r.z; o.w = v.w + r.w;
      *(float4*)&out[(size_t)grow * 384 + n0 + gg * 4] = o;
    }
  }
}

// -------- fused GEMM + residual + LayerNorm (proj1->ln2, proj2->ln3) -----------
__global__ __launch_bounds__(512, 2) void gemm_ln_k(
    const unsigned short* __restrict__ Ab, const unsigned short* __restrict__ Bt,
    const float* __restrict__ bias, const float* __restrict__ res,
    float* __restrict__ xc, const float* __restrict__ gamma,
    const float* __restrict__ beta, unsigned short* __restrict__ xn) {
  __shared__ unsigned short smem[28672];  // 56KB: stage (8K A + 48K B) / epi bounce
  __shared__ float part[64][8];
  unsigned short* sA = smem;
  unsigned short* sB = smem + 4096;
  const int tid = threadIdx.x;
  const int chunkg = gridDim.x >> 3;
  const int wg = blockIdx.x;
  const int lg = (wg & 7) * chunkg + (wg >> 3);
  const int m0 = lg * 64;
  const int wid = tid >> 6, lane = tid & 63;
  const int wr = wid >> 2, wcg = wid & 3;
  const int g = lane >> 4, c = lane & 15;

  f32x4 acc[2][6] = {};
  float biasr[6], gam[6], bet[6];
#pragma unroll
  for (int ni = 0; ni < 6; ++ni) {
    int col = wcg * 96 + ni * 16 + c;
    biasr[ni] = bias[col]; gam[ni] = gamma[col]; bet[ni] = beta[col];
  }

  for (int t = 0; t < 6; ++t) {
    const int k0 = t * 64;
    {
      int chunk = tid;
      int row = chunk >> 3, grp = chunk & 7;
      glds16(&Ab[(size_t)(m0 + row) * 384 + k0 + ((grp ^ (row & 7)) << 3)], &sA[chunk * 8]);
    }
#pragma unroll
    for (int p = 0; p < 6; ++p) {
      int chunk = p * 512 + tid;
      int row = chunk >> 3, grp = chunk & 7;
      glds16(&Bt[(size_t)row * 384 + k0 + ((grp ^ (row & 7)) << 3)], &sB[chunk * 8]);
    }
    vm_drain();
    __syncthreads();
#pragma unroll
    for (int kk = 0; kk < 2; ++kk) {
      short8 a[2], b[6];
#pragma unroll
      for (int mi = 0; mi < 2; ++mi) {
        int r = wr * 32 + mi * 16 + c;
        a[mi] = *(const short8*)&sA[r * 64 + (((kk * 4 + g) ^ (r & 7)) << 3)];
      }
#pragma unroll
      for (int ni = 0; ni < 6; ++ni) {
        int rb = wcg * 96 + ni * 16 + c;
        b[ni] = *(const short8*)&sB[rb * 64 + (((kk * 4 + g) ^ (rb & 7)) << 3)];
      }
#pragma unroll
      for (int mi = 0; mi < 2; ++mi)
#pragma unroll
        for (int ni = 0; ni < 6; ++ni)
          acc[mi][ni] = __builtin_amdgcn_mfma_f32_16x16x32_bf16(a[mi], b[ni], acc[mi][ni], 0, 0, 0);
    }
    __syncthreads();
  }

#pragma unroll
  for (int mi = 0; mi < 2; ++mi)
#pragma unroll
    for (int i = 0; i < 4; ++i) {
      int row = m0 + wr * 32 + mi * 16 + g * 4 + i;
#pragma unroll
      for (int ni = 0; ni < 6; ++ni)
        acc[mi][ni][i] += biasr[ni] + res[(size_t)row * 384 + wcg * 96 + ni * 16 + c];
    }

#pragma unroll
  for (int mi = 0; mi < 2; ++mi)
#pragma unroll
    for (int i = 0; i < 4; ++i) {
      float s = 0.f, q = 0.f;
#pragma unroll
      for (int ni = 0; ni < 6; ++ni) { float v = acc[mi][ni][i]; s += v; q += v * v; }
#pragma unroll
      for (int m = 1; m < 16; m <<= 1) { s += __shfl_xor(s, m); q += __shfl_xor(q, m); }
      if (c == 0) {
        int lr = wr * 32 + mi * 16 + g * 4 + i;
        part[lr][wcg] = s;
        part[lr][4 + wcg] = q;
      }
    }
  __syncthreads();
  float mu[2][4], rs[2][4];
#pragma unroll
  for (int mi = 0; mi < 2; ++mi)
#pragma unroll
    for (int i = 0; i < 4; ++i) {
      int lr = wr * 32 + mi * 16 + g * 4 + i;
      float s = part[lr][0] + part[lr][1] + part[lr][2] + part[lr][3];
      float q = part[lr][4] + part[lr][5] + part[lr][6] + part[lr][7];
      float m_ = s * (1.0f / 384.f);
      mu[mi][i] = m_;
      rs[mi][i] = rsqrtf(q * (1.0f / 384.f) - m_ * m_ + 1e-5f);
    }

  float* bf = (float*)smem;
#pragma unroll
  for (int h = 0; h < 2; ++h) {
    __syncthreads();
    if (wr == h) {
#pragma unroll
      for (int mi = 0; mi < 2; ++mi)
#pragma unroll
        for (int ni = 0; ni < 6; ++ni)
#pragma unroll
          for (int i = 0; i < 4; ++i) {
            int lr = mi * 16 + g * 4 + i;
            bf[lr * 388 + wcg * 96 + ni * 16 + c] = acc[mi][ni][i];
          }
    }
    __syncthreads();
#pragma unroll
    for (int p = 0; p < 6; ++p) {
      int chunk = p * 512 + tid;
      int row = chunk / 96, gg = chunk % 96;
      float4 v = *(const float4*)&bf[row * 388 + gg * 4];
      *(float4*)&xc[(size_t)(m0 + h * 32 + row) * 384 + gg * 4] = v;
    }
  }

  __syncthreads();
#pragma unroll
  for (int mi = 0; mi < 2; ++mi)
#pragma unroll
    for (int ni = 0; ni < 6; ++ni)
#pragma unroll
      for (int i = 0; i < 4; ++i) {
        int lr = wr * 32 + mi * 16 + g * 4 + i;
        smem[lr * 392 + wcg * 96 + ni * 16 + c] =
            f2bf((acc[mi][ni][i] - mu[mi][i]) * rs[mi][i] * gam[ni] + bet[ni]);
      }
  __syncthreads();
#pragma unroll
  for (int p = 0; p < 6; ++p) {
    int chunk = p * 512 + tid;
    int row = chunk / 48, c8 = chunk % 48;
    *(uint4*)&xn[(size_t)(m0 + row) * 384 + c8 * 8] = *(const uint4*)&smem[row * 392 + c8 * 8];
  }
}

// ---------------- attention (one block per (b,h,half), XCD-chunked grid) ----------
__device__ __forceinline__ int vt_off(int d, int sgrp) {
  return d * 256 + ((((sgrp + (d >> 3)) & 31) ^ (d & 7)) << 3);
}

template <bool CAUSAL>
__global__ __launch_bounds__(512, 2) void attn_k(const unsigned short* __restrict__ QKV,
                                                 unsigned short* __restrict__ O) {
  __shared__ unsigned short Ks[256 * 64];
  __shared__ unsigned short Vt[64 * 256];
  __shared__ unsigned short Ps[8][16 * 40];
  const int wg = blockIdx.x;
  const int lg = (wg & 7) * (gridDim.x >> 3) + (wg >> 3);
  const int bh = lg >> 1;
  const int half = lg & 1;
  const int b = bh / HH, hh = bh - b * HH;
  const int tid = threadIdx.x, wid = tid >> 6, lane = tid & 63;
  const int g = lane >> 4, c = lane & 15;
  const unsigned short* base = QKV + (size_t)b * TT * 1152;

#pragma unroll
  for (int t = 0; t < 4; ++t) {
    int chunk = t * 512 + tid;
    int s = chunk >> 3, grp = chunk & 7;
    *(uint4*)&Ks[s * 64 + ((grp ^ (s & 7)) << 3)] =
        *(const uint4*)&base[(size_t)s * 1152 + 384 + hh * 64 + grp * 8];
    union { unsigned short h[8]; uint4 u; } tv;
    tv.u = *(const uint4*)&base[(size_t)s * 1152 + 768 + hh * 64 + grp * 8];
#pragma unroll
    for (int j = 0; j < 8; ++j) Vt[vt_off(grp * 8 + j, s >> 3) + (s & 7)] = tv.h[j];
  }
  __syncthreads();

  const float scale = 0.05103103630798287f;  // 384^-0.5
  unsigned short* Pw = &Ps[wid][0];
  const int qr0 = half * 128 + wid * 16;

  short8 aq[2];
#pragma unroll
  for (int kk = 0; kk < 2; ++kk)
    aq[kk] = *(const short8*)&QKV[(size_t)(b * TT + qr0 + c) * 1152 + hh * 64 + kk * 32 + g * 8];

  f32x4 sacc[16] = {};
#pragma unroll
  for (int sj = 0; sj < 16; ++sj) {
    if (!CAUSAL || sj * 16 <= qr0) {
      int rk = sj * 16 + c;
      f32x4 z = sacc[sj];
      z = __builtin_amdgcn_mfma_f32_16x16x32_bf16(
          aq[0], *(const short8*)&Ks[rk * 64 + ((g ^ (rk & 7)) << 3)], z, 0, 0, 0);
      z = __builtin_amdgcn_mfma_f32_16x16x32_bf16(
          aq[1], *(const short8*)&Ks[rk * 64 + (((4 + g) ^ (rk & 7)) << 3)], z, 0, 0, 0);
      sacc[sj] = z;
    }
  }

  float inv[4];
#pragma unroll
  for (int i = 0; i < 4; ++i) {
    const int qr = qr0 + g * 4 + i;
    float mx = -1e30f;
#pragma unroll
    for (int sj = 0; sj < 16; ++sj) {
      if (!CAUSAL || sj * 16 <= qr0) {
        int s = sj * 16 + c;
        float v = sacc[sj][i] * scale;
        if (CAUSAL && s > qr) v = -1e30f;
        sacc[sj][i] = v;
        mx = fmaxf(mx, v);
      }
    }
#pragma unroll
    for (int m = 1; m < 16; m <<= 1) mx = fmaxf(mx, __shfl_xor(mx, m));
    float sum = 0.f;
#pragma unroll
    for (int sj = 0; sj < 16; ++sj) {
      if (!CAUSAL || sj * 16 <= qr0) {
        float p = __expf(sacc[sj][i] - mx);
        sacc[sj][i] = p;
        sum += p;
      }
    }
#pragma unroll
    for (int m = 1; m < 16; m <<= 1) sum += __shfl_xor(sum, m);
    inv[i] = 1.0f / sum;
  }

  f32x4 oacc[4] = {};
#pragma unroll
  for (int sk = 0; sk < 8; ++sk) {
    if (!CAUSAL || sk * 32 <= qr0) {
#pragma unroll
      for (int half_sj = 0; half_sj < 2; ++half_sj) {
        int sj = sk * 2 + half_sj;
#pragma unroll
        for (int i = 0; i < 4; ++i)
          Pw[(g * 4 + i) * 40 + half_sj * 16 + c] = f2bf(sacc[sj][i]);
      }
      short8 ap = *(const short8*)&Pw[c * 40 + g * 8];
#pragma unroll
      for (int dj = 0; dj < 4; ++dj) {
        short8 bv = *(const short8*)&Vt[vt_off(dj * 16 + c, sk * 4 + g)];
        oacc[dj] = __builtin_amdgcn_mfma_f32_16x16x32_bf16(ap, bv, oacc[dj], 0, 0, 0);
      }
    }
  }

  __syncthreads();
#pragma unroll
  for (int dj = 0; dj < 4; ++dj)
#pragma unroll
    for (int i = 0; i < 4; ++i) {
      int lr = wid * 16 + g * 4 + i;
      int col = dj * 16 + c;
      int gsw = (col >> 3) ^ ((lr >> 2) & 7);
      Ks[lr * 64 + gsw * 8 + (col & 7)] = f2bf(oacc[dj][i] * inv[i]);
    }
  __syncthreads();
#pragma unroll
  for (int it = 0; it < 2; ++it) {
    int chunk = it * 512 + tid;
    int row = chunk >> 3, c8 = chunk & 7;
    int gsw = c8 ^ ((row >> 2) & 7);
    *(uint4*)&O[(size_t)(b * TT + half * 128 + row) * CC + hh * 64 + c8 * 8] =
        *(const uint4*)&Ks[row * 64 + gsw * 8];
  }
}

// ---------------- launcher ----------------
extern "C" void kernel_launch(void* const* d_in, const int* in_sizes, int n_in,
                              void* d_out, int out_size, void* d_ws, size_t ws_size,
                              hipStream_t stream) {
  const float* x = (const float*)d_in[0];
  const float* enc = (const float*)d_in[1];
  const float* wq1 = (const float*)d_in[2];
  const float* wk1 = (const float*)d_in[3];
  const float* wv1 = (const float*)d_in[4];
  const float* proj1_w = (const float*)d_in[5];
  const float* proj1_b = (const float*)d_in[6];
  const float* wq2 = (const float*)d_in[7];
  const float* wk2 = (const float*)d_in[8];
  const float* wv2 = (const float*)d_in[9];
  const float* proj2_w = (const float*)d_in[10];
  const float* proj2_b = (const float*)d_in[11];
  const float* ffn_w1 = (const float*)d_in[12];
  const float* ffn_b1 = (const float*)d_in[13];
  const float* ffn_w2 = (const float*)d_in[14];
  const float* ffn_b2 = (const float*)d_in[15];
  const float* ln1_g = (const float*)d_in[16];
  const float* ln1_b = (const float*)d_in[17];
  const float* ln2_g = (const float*)d_in[18];
  const float* ln2_b = (const float*)d_in[19];
  const float* ln3_g = (const float*)d_in[20];
  const float* ln3_b = (const float*)d_in[21];
  float* out = (float*)d_out;

  char* ws = (char*)d_ws;
  const size_t OFF_A = 0;           // x_cur fp32 (B*T,384)        50331648
  const size_t OFF_X = 50331648;    // xn bf16 (B*T,384)           25165824
  const size_t OFF_Q = 75497472;    // QKV bf16 (B*T,1152) / h1 bf16 (B*T,1536)
  const size_t OFF_O = 150994944;   // O bf16 (B*T,384)            25165824
  const size_t OFF_W = 176160768;   // packed weights bf16          4718592

  float* xc = (float*)(ws + OFF_A);
  unsigned short* xn = (unsigned short*)(ws + OFF_X);
  unsigned short* qkv = (unsigned short*)(ws + OFF_Q);
  unsigned short* h1 = (unsigned short*)(ws + OFF_Q);  // aliased; qkv/obuf dead by FFN
  unsigned short* obuf = (unsigned short*)(ws + OFF_O);
  unsigned short* W = (unsigned short*)(ws + OFF_W);

  unsigned short* Wqkv1t = W + 0;        // 1152x384
  unsigned short* Wq2t = W + 442368;     // 384x384
  unsigned short* Wkv2t = W + 589824;    // 768x384
  unsigned short* proj1t = W + 884736;   // 384x384
  unsigned short* proj2t = W + 1032192;  // 384x384
  unsigned short* W1t = W + 1179648;     // 1536x384
  unsigned short* W2t = W + 1769472;     // 384x1536

  // ---- pack all weights ----
  pack_t_k<<<576, 256, 0, stream>>>(wq1, wk1, wv1, wq2, wk2, wv2,
                                    proj1_w, proj2_w, ffn_w1, ffn_w2, W);

  dim3 blk(256);
  // ---- layer 1: masked self-attention ----
  ln_k<<<8192, blk, 0, stream>>>(x, xn, ln1_g, ln1_b);
  gemm_k<0, false, 128><<<2304, blk, 0, stream>>>(xn, 384, Wqkv1t, 384, qkv, 1152,
                                                  nullptr, 384, 9);
  attn_k<true><<<1536, 512, 0, stream>>>(qkv, obuf);
  gemm_ln_k<<<512, 512, 0, stream>>>(obuf, proj1t, proj1_b, x, xc, ln2_g, ln2_b, xn);
  // ---- layer 2: cross-attention ----
  gemm_k<0, false, 128><<<768, blk, 0, stream>>>(xn, 384, Wq2t, 384, qkv, 1152,
                                                 nullptr, 384, 3);
  gemm_k<0, true, 128><<<1536, blk, 0, stream>>>(enc, 384, Wkv2t, 384, qkv + 384, 1152,
                                                 nullptr, 384, 6);
  attn_k<false><<<1536, 512, 0, stream>>>(qkv, obuf);
  gemm_ln_k<<<512, 512, 0, stream>>>(obuf, proj2t, proj2_b, xc, xc, ln3_g, ln3_b, xn);
  // ---- FFN ----
  gemm_k<1, false, 128><<<3072, blk, 0, stream>>>(xn, 384, W1t, 384, h1, 1536,
                                                  ffn_b1, 384, 12);
  ffn2_k<<<1024, blk, 0, stream>>>(h1, W2t, out, ffn_b2, xc);
}

// Round 19
// 391.816 us; speedup vs baseline: 1.0193x; 1.0193x over previous
//
#include <hip/hip_runtime.h>
#include <hip/hip_bf16.h>

// DecoderBlock: B=128, T=S=256, C=384, H=6, D=64. fp32 in/out, bf16 MFMA compute.
#define BB 128
#define TT 256
#define CC 384
#define HH 6
#define DD 64
#define NTOK 32768  // B*T

typedef __attribute__((ext_vector_type(8))) short short8;
typedef __attribute__((ext_vector_type(4))) float f32x4;

__device__ __forceinline__ unsigned short f2bf(float f) {
  union { float f; unsigned int u; } v; v.f = f;
  unsigned int r = v.u + 0x7fff + ((v.u >> 16) & 1);  // RNE
  return (unsigned short)(r >> 16);
}

__device__ __forceinline__ void glds16(const void* g, void* l) {
  __builtin_amdgcn_global_load_lds((const __attribute__((address_space(1))) void*)g,
                                   (__attribute__((address_space(3))) void*)l, 16, 0, 0);
}

__device__ __forceinline__ void vm_drain() {
  asm volatile("s_waitcnt vmcnt(0)" ::: "memory");
  __builtin_amdgcn_sched_barrier(0);
}

// ---------------- weight packing: LDS-tiled 64x64 transposes (full-line writes) ----
__global__ __launch_bounds__(256) void pack_t_k(
    const float* __restrict__ wq1, const float* __restrict__ wk1, const float* __restrict__ wv1,
    const float* __restrict__ wq2, const float* __restrict__ wk2, const float* __restrict__ wv2,
    const float* __restrict__ proj1_w, const float* __restrict__ proj2_w,
    const float* __restrict__ ffn_w1, const float* __restrict__ ffn_w2,
    unsigned short* __restrict__ W) {
  __shared__ unsigned short tile[64 * 72];
  const int id = blockIdx.x;
  const int tid = threadIdx.x;
  const float* src;
  unsigned short* dst;
  int ldIn, ldOut, i0, j0;
  if (id < 216) {  // 6 headstack weights x 6 heads x 6 tile-rows (384x64 per head)
    int w = id / 36, rem = id - w * 36;
    int h = rem / 6, tr = rem - h * 6;
    const float* bases[6] = {wq1, wk1, wv1, wq2, wk2, wv2};
    const int dstOff[6] = {0, 147456, 294912, 442368, 589824, 737280};
    src = bases[w] + h * 24576;
    dst = W + dstOff[w] + h * 24576;
    ldIn = 64; ldOut = 384; i0 = tr * 64; j0 = 0;
  } else if (id < 288) {  // proj1/proj2: 384x384, 6x6 tiles
    int t = id - 216;
    int which = t / 36; t -= which * 36;
    int tr = t / 6, tc = t - tr * 6;
    src = which ? proj2_w : proj1_w;
    dst = W + (which ? 1032192 : 884736);
    ldIn = 384; ldOut = 384; i0 = tr * 64; j0 = tc * 64;
  } else if (id < 432) {  // ffn_w1: 384x1536, 6x24 tiles
    int t = id - 288;
    int tr = t / 24, tc = t - tr * 24;
    src = ffn_w1; dst = W + 1179648;
    ldIn = 1536; ldOut = 384; i0 = tr * 64; j0 = tc * 64;
  } else {  // ffn_w2: 1536x384, 24x6 tiles
    int t = id - 432;
    int tr = t / 6, tc = t - tr * 6;
    src = ffn_w2; dst = W + 1769472;
    ldIn = 384; ldOut = 1536; i0 = tr * 64; j0 = tc * 64;
  }
#pragma unroll
  for (int p = 0; p < 4; ++p) {
    int chunk = p * 256 + tid;  // 1024 float4 reads
    int r = chunk >> 4, c4 = chunk & 15;
    float4 f = *(const float4*)&src[(size_t)(i0 + r) * ldIn + j0 + c4 * 4];
    tile[(c4 * 4 + 0) * 72 + r] = f2bf(f.x);
    tile[(c4 * 4 + 1) * 72 + r] = f2bf(f.y);
    tile[(c4 * 4 + 2) * 72 + r] = f2bf(f.z);
    tile[(c4 * 4 + 3) * 72 + r] = f2bf(f.w);
  }
  __syncthreads();
#pragma unroll
  for (int p = 0; p < 2; ++p) {
    int chunk = p * 256 + tid;  // 512 uint4 writes
    int j = chunk >> 3, i8 = chunk & 7;
    *(uint4*)&dst[(size_t)(j0 + j) * ldOut + i0 + i8 * 8] = *(const uint4*)&tile[j * 72 + i8 * 8];
  }
}

// ---------------- layernorm (fp32 in -> bf16 out), float2-vectorized ----------------
__global__ __launch_bounds__(256) void ln_k(const float* __restrict__ x,
                                            unsigned short* __restrict__ out,
                                            const float* __restrict__ gamma,
                                            const float* __restrict__ beta) {
  int row = blockIdx.x * 4 + (threadIdx.x >> 6);
  int lane = threadIdx.x & 63;
  const float2* xr = (const float2*)(x + (size_t)row * CC);
  float2 v[3];
  float s = 0.f;
#pragma unroll
  for (int j = 0; j < 3; ++j) { v[j] = xr[j * 64 + lane]; s += v[j].x + v[j].y; }
#pragma unroll
  for (int m = 1; m < 64; m <<= 1) s += __shfl_xor(s, m);
  float mu = s * (1.0f / CC);
  float vs = 0.f;
#pragma unroll
  for (int j = 0; j < 3; ++j) {
    float dx = v[j].x - mu, dy = v[j].y - mu;
    vs += dx * dx + dy * dy;
  }
#pragma unroll
  for (int m = 1; m < 64; m <<= 1) vs += __shfl_xor(vs, m);
  float rs = rsqrtf(vs * (1.0f / CC) + 1e-5f);
  unsigned int* orow = (unsigned int*)(out + (size_t)row * CC);
#pragma unroll
  for (int j = 0; j < 3; ++j) {
    int cidx = j * 64 + lane;
    float2 gmm = ((const float2*)gamma)[cidx];
    float2 bt = ((const float2*)beta)[cidx];
    unsigned int lo = f2bf((v[j].x - mu) * rs * gmm.x + bt.x);
    unsigned int hi = f2bf((v[j].y - mu) * rs * gmm.y + bt.y);
    orow[cidx] = lo | (hi << 16);
  }
}

// ---------------- GEMM: C(MxN) = A(MxK) * Bt(NxK)^T ----------
// BMx128 tile, 4 waves, single-buffer glds staging, full drain per step.
// EPI 0: bf16 out; EPI 1: bf16 relu+bias; EPI 2: fp32 res+bias (res PREFETCHED into
// registers before the K-loop; fp32 LDS bounce epilogue, full-line float4 stores).
template <int EPI, bool AF32, int BM>
__global__ __launch_bounds__(256) void gemm_k(const void* __restrict__ Ap, int lda,
                                              const unsigned short* __restrict__ Bt, int ldb,
                                              void* __restrict__ Cp, int ldc,
                                              const float* __restrict__ bias,
                                              const float* __restrict__ res, int ldres,
                                              int K, int nx) {
  constexpr int MI = BM / 32;
  constexpr int APASS = BM * 8 / 256;
  constexpr int SMEMN = (EPI == 2) ? (BM * 256) : (BM * 64 + 8192);  // ushorts
  __shared__ unsigned short smem[SMEMN];
  unsigned short* sA = smem;
  unsigned short* sB = smem + BM * 64;
  const int tid = threadIdx.x;
  const int chunkg = gridDim.x >> 3;
  const int wg = blockIdx.x;
  const int lg = (wg & 7) * chunkg + (wg >> 3);
  const int bx = lg % nx, by = lg / nx;
  const int m0 = by * BM;
  const int n0 = bx * 128;
  const int wid = tid >> 6, lane = tid & 63;
  const int wr = wid >> 1, wc = wid & 1;
  const int g = lane >> 4, c = lane & 15;

  f32x4 acc[MI][4] = {};
  float biasr[4];
  if (EPI >= 1) {
#pragma unroll
    for (int ni = 0; ni < 4; ++ni) biasr[ni] = bias[n0 + wc * 64 + ni * 16 + c];
  }

  // EPI2: prefetch residual in STORE-PASS layout before the K-loop (latency hidden)
  float4 resr[(EPI == 2) ? (BM / 8) : 1];
  if (EPI == 2) {
#pragma unroll
    for (int it = 0; it < BM / 8; ++it) {
      int chunk = it * 256 + tid;
      int row = chunk >> 5, gg = chunk & 31;
      resr[it] = *(const float4*)&res[(size_t)(m0 + row) * ldres + n0 + gg * 4];
    }
  }

  const int nt = K >> 6;
  for (int t = 0; t < nt; ++t) {
    const int k0 = t * 64;
    if constexpr (!AF32) {
#pragma unroll
      for (int p = 0; p < APASS; ++p) {
        int chunk = p * 256 + tid;
        int row = chunk >> 3, grp = chunk & 7;
        const unsigned short* Ab = (const unsigned short*)Ap;
        glds16(&Ab[(size_t)(m0 + row) * lda + k0 + ((grp ^ (row & 7)) << 3)], &sA[chunk * 8]);
      }
    } else {
#pragma unroll
      for (int p = 0; p < APASS; ++p) {
        int chunk = p * 256 + tid;
        int row = chunk >> 3, grp = chunk & 7;
        int dst = row * 64 + ((grp ^ (row & 7)) << 3);
        const float* Af = (const float*)Ap + (size_t)(m0 + row) * lda + k0 + grp * 8;
        float4 f0 = *(const float4*)Af;
        float4 f1 = *(const float4*)(Af + 4);
        union { unsigned short h[8]; uint4 u; } t2;
        t2.h[0] = f2bf(f0.x); t2.h[1] = f2bf(f0.y); t2.h[2] = f2bf(f0.z); t2.h[3] = f2bf(f0.w);
        t2.h[4] = f2bf(f1.x); t2.h[5] = f2bf(f1.y); t2.h[6] = f2bf(f1.z); t2.h[7] = f2bf(f1.w);
        *(uint4*)&sA[dst] = t2.u;
      }
    }
#pragma unroll
    for (int p = 0; p < 4; ++p) {
      int chunk = p * 256 + tid;
      int row = chunk >> 3, grp = chunk & 7;
      glds16(&Bt[(size_t)(n0 + row) * ldb + k0 + ((grp ^ (row & 7)) << 3)], &sB[chunk * 8]);
    }
    vm_drain();
    __syncthreads();
#pragma unroll
    for (int kk = 0; kk < 2; ++kk) {
      short8 a[MI], b[4];
#pragma unroll
      for (int mi = 0; mi < MI; ++mi) {
        int r = wr * (BM / 2) + mi * 16 + c;
        a[mi] = *(const short8*)&sA[r * 64 + (((kk * 4 + g) ^ (r & 7)) << 3)];
      }
#pragma unroll
      for (int ni = 0; ni < 4; ++ni) {
        int rb = wc * 64 + ni * 16 + c;
        b[ni] = *(const short8*)&sB[rb * 64 + (((kk * 4 + g) ^ (rb & 7)) << 3)];
      }
#pragma unroll
      for (int mi = 0; mi < MI; ++mi)
#pragma unroll
        for (int ni = 0; ni < 4; ++ni)
          acc[mi][ni] = __builtin_amdgcn_mfma_f32_16x16x32_bf16(a[mi], b[ni], acc[mi][ni], 0, 0, 0);
    }
    __syncthreads();
  }

  if (EPI <= 1) {
#pragma unroll
    for (int mi = 0; mi < MI; ++mi)
#pragma unroll
      for (int ni = 0; ni < 4; ++ni)
#pragma unroll
        for (int i = 0; i < 4; ++i) {
          int row = wr * (BM / 2) + mi * 16 + g * 4 + i;
          int col = wc * 64 + ni * 16 + c;
          float v = acc[mi][ni][i];
          if (EPI == 1) v = fmaxf(v + biasr[ni], 0.f);
          int gsw = (col >> 3) ^ ((row >> 2) & 7);
          smem[row * 128 + gsw * 8 + (col & 7)] = f2bf(v);
        }
    __syncthreads();
#pragma unroll
    for (int it = 0; it < BM / 16; ++it) {
      int chunk = it * 256 + tid;
      int row = chunk >> 4, c16 = chunk & 15;
      int gsw = c16 ^ ((row >> 2) & 7);
      *(uint4*)&((unsigned short*)Cp)[(size_t)(m0 + row) * ldc + n0 + c16 * 8] =
          *(const uint4*)&smem[row * 128 + gsw * 8];
    }
  } else {
    float* smf = (float*)smem;
#pragma unroll
    for (int mi = 0; mi < MI; ++mi)
#pragma unroll
      for (int ni = 0; ni < 4; ++ni)
#pragma unroll
        for (int i = 0; i < 4; ++i) {
          int row = wr * (BM / 2) + mi * 16 + g * 4 + i;
          int col = wc * 64 + ni * 16 + c;
          int gg = col >> 2;
          int sg = gg ^ (row & 7);
          smf[row * 128 + sg * 4 + (col & 3)] = acc[mi][ni][i] + biasr[ni];
        }
    __syncthreads();
#pragma unroll
    for (int it = 0; it < BM / 8; ++it) {
      int chunk = it * 256 + tid;
      int row = chunk >> 5, gg = chunk & 31;
      int sg = gg ^ (row & 7);
      float4 v = *(const float4*)&smf[row * 128 + sg * 4];
      float4 r = resr[it];
      float4 o;
      o.x = v.x + r.x; o.y = v.y + r.y; o.z = v.z + r.z; o.w = v.w + r.w;
      *(float4*)&((float*)Cp)[(size_t)(m0 + row) * ldc + n0 + gg * 4] = o;
    }
  }
}

// -------- fused GEMM + residual + LayerNorm (proj1->ln2, proj2->ln3) -----------
__global__ __launch_bounds__(512, 2) void gemm_ln_k(
    const unsigned short* __restrict__ Ab, const unsigned short* __restrict__ Bt,
    const float* __restrict__ bias, const float* __restrict__ res,
    float* __restrict__ xc, const float* __restrict__ gamma,
    const float* __restrict__ beta, unsigned short* __restrict__ xn) {
  __shared__ unsigned short smem[28672];  // 56KB: stage (8K A + 48K B) / epi bounce
  __shared__ float part[64][8];
  unsigned short* sA = smem;
  unsigned short* sB = smem + 4096;
  const int tid = threadIdx.x;
  const int chunkg = gridDim.x >> 3;
  const int wg = blockIdx.x;
  const int lg = (wg & 7) * chunkg + (wg >> 3);
  const int m0 = lg * 64;
  const int wid = tid >> 6, lane = tid & 63;
  const int wr = wid >> 2, wcg = wid & 3;
  const int g = lane >> 4, c = lane & 15;

  f32x4 acc[2][6] = {};
  float biasr[6], gam[6], bet[6];
#pragma unroll
  for (int ni = 0; ni < 6; ++ni) {
    int col = wcg * 96 + ni * 16 + c;
    biasr[ni] = bias[col]; gam[ni] = gamma[col]; bet[ni] = beta[col];
  }

  for (int t = 0; t < 6; ++t) {
    const int k0 = t * 64;
    {
      int chunk = tid;
      int row = chunk >> 3, grp = chunk & 7;
      glds16(&Ab[(size_t)(m0 + row) * 384 + k0 + ((grp ^ (row & 7)) << 3)], &sA[chunk * 8]);
    }
#pragma unroll
    for (int p = 0; p < 6; ++p) {
      int chunk = p * 512 + tid;
      int row = chunk >> 3, grp = chunk & 7;
      glds16(&Bt[(size_t)row * 384 + k0 + ((grp ^ (row & 7)) << 3)], &sB[chunk * 8]);
    }
    vm_drain();
    __syncthreads();
#pragma unroll
    for (int kk = 0; kk < 2; ++kk) {
      short8 a[2], b[6];
#pragma unroll
      for (int mi = 0; mi < 2; ++mi) {
        int r = wr * 32 + mi * 16 + c;
        a[mi] = *(const short8*)&sA[r * 64 + (((kk * 4 + g) ^ (r & 7)) << 3)];
      }
#pragma unroll
      for (int ni = 0; ni < 6; ++ni) {
        int rb = wcg * 96 + ni * 16 + c;
        b[ni] = *(const short8*)&sB[rb * 64 + (((kk * 4 + g) ^ (rb & 7)) << 3)];
      }
#pragma unroll
      for (int mi = 0; mi < 2; ++mi)
#pragma unroll
        for (int ni = 0; ni < 6; ++ni)
          acc[mi][ni] = __builtin_amdgcn_mfma_f32_16x16x32_bf16(a[mi], b[ni], acc[mi][ni], 0, 0, 0);
    }
    __syncthreads();
  }

#pragma unroll
  for (int mi = 0; mi < 2; ++mi)
#pragma unroll
    for (int i = 0; i < 4; ++i) {
      int row = m0 + wr * 32 + mi * 16 + g * 4 + i;
#pragma unroll
      for (int ni = 0; ni < 6; ++ni)
        acc[mi][ni][i] += biasr[ni] + res[(size_t)row * 384 + wcg * 96 + ni * 16 + c];
    }

#pragma unroll
  for (int mi = 0; mi < 2; ++mi)
#pragma unroll
    for (int i = 0; i < 4; ++i) {
      float s = 0.f, q = 0.f;
#pragma unroll
      for (int ni = 0; ni < 6; ++ni) { float v = acc[mi][ni][i]; s += v; q += v * v; }
#pragma unroll
      for (int m = 1; m < 16; m <<= 1) { s += __shfl_xor(s, m); q += __shfl_xor(q, m); }
      if (c == 0) {
        int lr = wr * 32 + mi * 16 + g * 4 + i;
        part[lr][wcg] = s;
        part[lr][4 + wcg] = q;
      }
    }
  __syncthreads();
  float mu[2][4], rs[2][4];
#pragma unroll
  for (int mi = 0; mi < 2; ++mi)
#pragma unroll
    for (int i = 0; i < 4; ++i) {
      int lr = wr * 32 + mi * 16 + g * 4 + i;
      float s = part[lr][0] + part[lr][1] + part[lr][2] + part[lr][3];
      float q = part[lr][4] + part[lr][5] + part[lr][6] + part[lr][7];
      float m_ = s * (1.0f / 384.f);
      mu[mi][i] = m_;
      rs[mi][i] = rsqrtf(q * (1.0f / 384.f) - m_ * m_ + 1e-5f);
    }

  float* bf = (float*)smem;
#pragma unroll
  for (int h = 0; h < 2; ++h) {
    __syncthreads();
    if (wr == h) {
#pragma unroll
      for (int mi = 0; mi < 2; ++mi)
#pragma unroll
        for (int ni = 0; ni < 6; ++ni)
#pragma unroll
          for (int i = 0; i < 4; ++i) {
            int lr = mi * 16 + g * 4 + i;
            bf[lr * 388 + wcg * 96 + ni * 16 + c] = acc[mi][ni][i];
          }
    }
    __syncthreads();
#pragma unroll
    for (int p = 0; p < 6; ++p) {
      int chunk = p * 512 + tid;
      int row = chunk / 96, gg = chunk % 96;
      float4 v = *(const float4*)&bf[row * 388 + gg * 4];
      *(float4*)&xc[(size_t)(m0 + h * 32 + row) * 384 + gg * 4] = v;
    }
  }

  __syncthreads();
#pragma unroll
  for (int mi = 0; mi < 2; ++mi)
#pragma unroll
    for (int ni = 0; ni < 6; ++ni)
#pragma unroll
      for (int i = 0; i < 4; ++i) {
        int lr = wr * 32 + mi * 16 + g * 4 + i;
        smem[lr * 392 + wcg * 96 + ni * 16 + c] =
            f2bf((acc[mi][ni][i] - mu[mi][i]) * rs[mi][i] * gam[ni] + bet[ni]);
      }
  __syncthreads();
#pragma unroll
  for (int p = 0; p < 6; ++p) {
    int chunk = p * 512 + tid;
    int row = chunk / 48, c8 = chunk % 48;
    *(uint4*)&xn[(size_t)(m0 + row) * 384 + c8 * 8] = *(const uint4*)&smem[row * 392 + c8 * 8];
  }
}

// ---------------- attention (one block per (b,h,half), XCD-chunked grid) ----------
__device__ __forceinline__ int vt_off(int d, int sgrp) {
  return d * 256 + ((((sgrp + (d >> 3)) & 31) ^ (d & 7)) << 3);
}

template <bool CAUSAL>
__global__ __launch_bounds__(512, 2) void attn_k(const unsigned short* __restrict__ QKV,
                                                 unsigned short* __restrict__ O) {
  __shared__ unsigned short Ks[256 * 64];
  __shared__ unsigned short Vt[64 * 256];
  __shared__ unsigned short Ps[8][16 * 40];
  // XCD-chunked bijective swizzle (gridDim.x == 1536, %8 == 0): the 12 blocks
  // sharing one batch's qkv slice land on the same XCD's L2.
  const int wg = blockIdx.x;
  const int lg = (wg & 7) * (gridDim.x >> 3) + (wg >> 3);
  const int bh = lg >> 1;
  const int half = lg & 1;
  const int b = bh / HH, hh = bh - b * HH;
  const int tid = threadIdx.x, wid = tid >> 6, lane = tid & 63;
  const int g = lane >> 4, c = lane & 15;
  const unsigned short* base = QKV + (size_t)b * TT * 1152;

#pragma unroll
  for (int t = 0; t < 4; ++t) {
    int chunk = t * 512 + tid;
    int s = chunk >> 3, grp = chunk & 7;
    *(uint4*)&Ks[s * 64 + ((grp ^ (s & 7)) << 3)] =
        *(const uint4*)&base[(size_t)s * 1152 + 384 + hh * 64 + grp * 8];
    union { unsigned short h[8]; uint4 u; } tv;
    tv.u = *(const uint4*)&base[(size_t)s * 1152 + 768 + hh * 64 + grp * 8];
#pragma unroll
    for (int j = 0; j < 8; ++j) Vt[vt_off(grp * 8 + j, s >> 3) + (s & 7)] = tv.h[j];
  }
  __syncthreads();

  const float scale = 0.05103103630798287f;  // 384^-0.5
  unsigned short* Pw = &Ps[wid][0];
  const int qr0 = half * 128 + wid * 16;

  short8 aq[2];
#pragma unroll
  for (int kk = 0; kk < 2; ++kk)
    aq[kk] = *(const short8*)&QKV[(size_t)(b * TT + qr0 + c) * 1152 + hh * 64 + kk * 32 + g * 8];

  f32x4 sacc[16] = {};
#pragma unroll
  for (int sj = 0; sj < 16; ++sj) {
    if (!CAUSAL || sj * 16 <= qr0) {
      int rk = sj * 16 + c;
      f32x4 z = sacc[sj];
      z = __builtin_amdgcn_mfma_f32_16x16x32_bf16(
          aq[0], *(const short8*)&Ks[rk * 64 + ((g ^ (rk & 7)) << 3)], z, 0, 0, 0);
      z = __builtin_amdgcn_mfma_f32_16x16x32_bf16(
          aq[1], *(const short8*)&Ks[rk * 64 + (((4 + g) ^ (rk & 7)) << 3)], z, 0, 0, 0);
      sacc[sj] = z;
    }
  }

  float inv[4];
#pragma unroll
  for (int i = 0; i < 4; ++i) {
    const int qr = qr0 + g * 4 + i;
    float mx = -1e30f;
#pragma unroll
    for (int sj = 0; sj < 16; ++sj) {
      if (!CAUSAL || sj * 16 <= qr0) {
        int s = sj * 16 + c;
        float v = sacc[sj][i] * scale;
        if (CAUSAL && s > qr) v = -1e30f;
        sacc[sj][i] = v;
        mx = fmaxf(mx, v);
      }
    }
#pragma unroll
    for (int m = 1; m < 16; m <<= 1) mx = fmaxf(mx, __shfl_xor(mx, m));
    float sum = 0.f;
#pragma unroll
    for (int sj = 0; sj < 16; ++sj) {
      if (!CAUSAL || sj * 16 <= qr0) {
        float p = __expf(sacc[sj][i] - mx);
        sacc[sj][i] = p;
        sum += p;
      }
    }
#pragma unroll
    for (int m = 1; m < 16; m <<= 1) sum += __shfl_xor(sum, m);
    inv[i] = 1.0f / sum;
  }

  f32x4 oacc[4] = {};
#pragma unroll
  for (int sk = 0; sk < 8; ++sk) {
    if (!CAUSAL || sk * 32 <= qr0) {
#pragma unroll
      for (int half_sj = 0; half_sj < 2; ++half_sj) {
        int sj = sk * 2 + half_sj;
#pragma unroll
        for (int i = 0; i < 4; ++i)
          Pw[(g * 4 + i) * 40 + half_sj * 16 + c] = f2bf(sacc[sj][i]);
      }
      short8 ap = *(const short8*)&Pw[c * 40 + g * 8];
#pragma unroll
      for (int dj = 0; dj < 4; ++dj) {
        short8 bv = *(const short8*)&Vt[vt_off(dj * 16 + c, sk * 4 + g)];
        oacc[dj] = __builtin_amdgcn_mfma_f32_16x16x32_bf16(ap, bv, oacc[dj], 0, 0, 0);
      }
    }
  }

  __syncthreads();
#pragma unroll
  for (int dj = 0; dj < 4; ++dj)
#pragma unroll
    for (int i = 0; i < 4; ++i) {
      int lr = wid * 16 + g * 4 + i;
      int col = dj * 16 + c;
      int gsw = (col >> 3) ^ ((lr >> 2) & 7);
      Ks[lr * 64 + gsw * 8 + (col & 7)] = f2bf(oacc[dj][i] * inv[i]);
    }
  __syncthreads();
#pragma unroll
  for (int it = 0; it < 2; ++it) {
    int chunk = it * 512 + tid;
    int row = chunk >> 3, c8 = chunk & 7;
    int gsw = c8 ^ ((row >> 2) & 7);
    *(uint4*)&O[(size_t)(b * TT + half * 128 + row) * CC + hh * 64 + c8 * 8] =
        *(const uint4*)&Ks[row * 64 + gsw * 8];
  }
}

// ---------------- launcher ----------------
extern "C" void kernel_launch(void* const* d_in, const int* in_sizes, int n_in,
                              void* d_out, int out_size, void* d_ws, size_t ws_size,
                              hipStream_t stream) {
  const float* x = (const float*)d_in[0];
  const float* enc = (const float*)d_in[1];
  const float* wq1 = (const float*)d_in[2];
  const float* wk1 = (const float*)d_in[3];
  const float* wv1 = (const float*)d_in[4];
  const float* proj1_w = (const float*)d_in[5];
  const float* proj1_b = (const float*)d_in[6];
  const float* wq2 = (const float*)d_in[7];
  const float* wk2 = (const float*)d_in[8];
  const float* wv2 = (const float*)d_in[9];
  const float* proj2_w = (const float*)d_in[10];
  const float* proj2_b = (const float*)d_in[11];
  const float* ffn_w1 = (const float*)d_in[12];
  const float* ffn_b1 = (const float*)d_in[13];
  const float* ffn_w2 = (const float*)d_in[14];
  const float* ffn_b2 = (const float*)d_in[15];
  const float* ln1_g = (const float*)d_in[16];
  const float* ln1_b = (const float*)d_in[17];
  const float* ln2_g = (const float*)d_in[18];
  const float* ln2_b = (const float*)d_in[19];
  const float* ln3_g = (const float*)d_in[20];
  const float* ln3_b = (const float*)d_in[21];
  float* out = (float*)d_out;

  char* ws = (char*)d_ws;
  const size_t OFF_A = 0;           // x_cur fp32 (B*T,384)        50331648
  const size_t OFF_X = 50331648;    // xn bf16 (B*T,384)           25165824
  const size_t OFF_Q = 75497472;    // QKV bf16 (B*T,1152) / h1 bf16 (B*T,1536)
  const size_t OFF_O = 150994944;   // O bf16 (B*T,384)            25165824
  const size_t OFF_W = 176160768;   // packed weights bf16          4718592

  float* xc = (float*)(ws + OFF_A);
  unsigned short* xn = (unsigned short*)(ws + OFF_X);
  unsigned short* qkv = (unsigned short*)(ws + OFF_Q);
  unsigned short* h1 = (unsigned short*)(ws + OFF_Q);  // aliased; qkv/obuf dead by FFN
  unsigned short* obuf = (unsigned short*)(ws + OFF_O);
  unsigned short* W = (unsigned short*)(ws + OFF_W);

  unsigned short* Wqkv1t = W + 0;        // 1152x384
  unsigned short* Wq2t = W + 442368;     // 384x384
  unsigned short* Wkv2t = W + 589824;    // 768x384
  unsigned short* proj1t = W + 884736;   // 384x384
  unsigned short* proj2t = W + 1032192;  // 384x384
  unsigned short* W1t = W + 1179648;     // 1536x384
  unsigned short* W2t = W + 1769472;     // 384x1536

  // ---- pack all weights ----
  pack_t_k<<<576, 256, 0, stream>>>(wq1, wk1, wv1, wq2, wk2, wv2,
                                    proj1_w, proj2_w, ffn_w1, ffn_w2, W);

  dim3 blk(256);
  // ---- layer 1: masked self-attention ----
  ln_k<<<8192, blk, 0, stream>>>(x, xn, ln1_g, ln1_b);
  gemm_k<0, false, 128><<<2304, blk, 0, stream>>>(xn, 384, Wqkv1t, 384, qkv, 1152,
                                                  nullptr, nullptr, 0, 384, 9);
  attn_k<true><<<1536, 512, 0, stream>>>(qkv, obuf);
  gemm_ln_k<<<512, 512, 0, stream>>>(obuf, proj1t, proj1_b, x, xc, ln2_g, ln2_b, xn);
  // ---- layer 2: cross-attention ----
  gemm_k<0, false, 128><<<768, blk, 0, stream>>>(xn, 384, Wq2t, 384, qkv, 1152,
                                                 nullptr, nullptr, 0, 384, 3);
  gemm_k<0, true, 128><<<1536, blk, 0, stream>>>(enc, 384, Wkv2t, 384, qkv + 384, 1152,
                                                 nullptr, nullptr, 0, 384, 6);
  attn_k<false><<<1536, 512, 0, stream>>>(qkv, obuf);
  gemm_ln_k<<<512, 512, 0, stream>>>(obuf, proj2t, proj2_b, xc, xc, ln3_g, ln3_b, xn);
  // ---- FFN ----
  gemm_k<1, false, 128><<<3072, blk, 0, stream>>>(xn, 384, W1t, 384, h1, 1536,
                                                  ffn_b1, nullptr, 0, 384, 12);
  gemm_k<2, false, 64><<<1536, blk, 0, stream>>>(h1, 1536, W2t, 1536, out, 384,
                                                 ffn_b2, xc, 384, 1536, 3);
}